// Round 1
// baseline (527.919 us; speedup 1.0000x reference)
//
#include <hip/hip_runtime.h>
#include <hip/hip_bf16.h>

typedef __attribute__((ext_vector_type(8))) short short8;
typedef __attribute__((ext_vector_type(4))) float f32x4;

#define N_EMBED 2048
#define N_HEAD 16
#define D_KV 128
#define D_C 64
#define D_R 64
#define D_H 128
#define BB 2
#define SS 2048
#define NTOK (BB*SS)          // 4096

__device__ __forceinline__ unsigned short f2bf(float f) {
    unsigned int b = __builtin_bit_cast(unsigned int, f);
    b += 0x7fffu + ((b >> 16) & 1u);
    return (unsigned short)(b >> 16);
}
__device__ __forceinline__ float bf2f(unsigned short u) {
    unsigned int b = ((unsigned int)u) << 16;
    return __builtin_bit_cast(float, b);
}

// ---------------- conversion kernels ----------------

__global__ void conv_f32_bf16(const float* __restrict__ in, unsigned short* __restrict__ out, int n) {
    int i = (blockIdx.x * 256 + threadIdx.x) * 4;
    if (i >= n) return;
    float4 v = *(const float4*)(in + i);
    ushort4 o;
    o.x = f2bf(v.x); o.y = f2bf(v.y); o.z = f2bf(v.z); o.w = f2bf(v.w);
    *(ushort4*)(out + i) = o;
}

// Wcat_T [320][2048]: rows 0-127 = W_dkv col, 128-255 = W_dq, 256-319 = W_kr
__global__ void build_wcat(const float* __restrict__ Wdkv, const float* __restrict__ Wdq,
                           const float* __restrict__ Wkr, unsigned short* __restrict__ out) {
    int i = blockIdx.x * 256 + threadIdx.x;          // over 2048*320, input-coalesced
    int k = i / 320, n = i % 320;
    float v;
    if (n < 128)      v = Wdkv[k * 128 + n];
    else if (n < 256) v = Wdq[k * 128 + (n - 128)];
    else              v = Wkr[k * 64 + (n - 256)];
    out[(size_t)n * 2048 + k] = f2bf(v);
}

// Wq_T [2048][128]: row n = h*128+c; c<64 from W_qc, else W_qr
__global__ void build_wq(const float* __restrict__ Wqc, const float* __restrict__ Wqr,
                         unsigned short* __restrict__ out) {
    int i = blockIdx.x * 256 + threadIdx.x;          // over 128*2048
    int k = i >> 11, n = i & 2047;
    int h = n >> 7, c = n & 127;
    float v = (c < 64) ? Wqc[(h * 128 + k) * 64 + c] : Wqr[(h * 128 + k) * 64 + (c - 64)];
    out[(size_t)n * 128 + k] = f2bf(v);
}

// Wkv_T [3072][128]: row n = h*192+c; c<64 from W_uk, else W_uv
__global__ void build_wkv(const float* __restrict__ Wuk, const float* __restrict__ Wuv,
                          unsigned short* __restrict__ out) {
    int i = blockIdx.x * 256 + threadIdx.x;          // over 128*3072
    int k = i / 3072, n = i % 3072;
    int h = n / 192, c = n % 192;
    float v = (c < 64) ? Wuk[(h * 128 + k) * 64 + c] : Wuv[(h * 128 + k) * 128 + (c - 64)];
    out[(size_t)n * 128 + k] = f2bf(v);
}

// Wo_T [2048][2048]: out[n][k] = W_o[k][n]
__global__ void build_wo(const float* __restrict__ Wo, unsigned short* __restrict__ out) {
    int i = blockIdx.x * 256 + threadIdx.x;          // over 2048*2048, input-coalesced
    int k = i >> 11, n = i & 2047;
    out[(size_t)n * 2048 + k] = f2bf(Wo[(size_t)k * 2048 + n]);
}

// ---------------- rope ----------------

#define ROPE_COEF (-0.28782313662425575f)  // -ln(10000)/32

__global__ void rope_k_kernel(unsigned short* __restrict__ g1) {
    int i = blockIdx.x * 256 + threadIdx.x;   // NTOK*32
    int j = i & 31, row = i >> 5;
    int pos = row & (SS - 1);
    float freq = __expf(ROPE_COEF * (float)j);
    float a = (float)pos * freq;
    float s, c;
    __sincosf(a, &s, &c);
    unsigned short* p = g1 + (size_t)row * 320 + 256 + 2 * j;
    float x0 = bf2f(p[0]), x1 = bf2f(p[1]);
    p[0] = f2bf(x0 * c - x1 * s);
    p[1] = f2bf(x0 * s + x1 * c);
}

__global__ void rope_q_kernel(unsigned short* __restrict__ q) {
    int i = blockIdx.x * 256 + threadIdx.x;   // NTOK*16*32
    int j = i & 31, h = (i >> 5) & 15, row = i >> 9;
    int pos = row & (SS - 1);
    float freq = __expf(ROPE_COEF * (float)j);
    float a = (float)pos * freq;
    float s, c;
    __sincosf(a, &s, &c);
    unsigned short* p = q + (size_t)row * 2048 + h * 128 + 64 + 2 * j;
    float x0 = bf2f(p[0]), x1 = bf2f(p[1]);
    p[0] = f2bf(x0 * c - x1 * s);
    p[1] = f2bf(x0 * s + x1 * c);
}

// ---------------- GEMM: C[M,N] = A[M,K] * Bt[N,K]^T ----------------

__device__ __forceinline__ void store_c(float* p, float v) { *p = v; }
__device__ __forceinline__ void store_c(unsigned short* p, float v) { *p = f2bf(v); }

template <int BN, typename CT>
__global__ __launch_bounds__(256) void gemm_bf16_kernel(
    const unsigned short* __restrict__ A, int lda,
    const unsigned short* __restrict__ Bt, int ldb,
    CT* __restrict__ C, int ldc,
    int M, int N, int K) {
    constexpr int BM = 128, BK = 32, PAD = 8;
    __shared__ __align__(16) unsigned short As[BM][BK + PAD];
    __shared__ __align__(16) unsigned short Bs[BN][BK + PAD];
    constexpr int WM = 64, WN = BN / 2;
    constexpr int FM = WM / 16, FN = WN / 16;
    const int tid = threadIdx.x, wave = tid >> 6, lane = tid & 63;
    const int wr = wave >> 1, wc = wave & 1;
    const int lg = lane >> 4, lr = lane & 15;
    const int m0 = blockIdx.y * BM, n0 = blockIdx.x * BN;

    f32x4 acc[FM][FN] = {};

    for (int k0 = 0; k0 < K; k0 += BK) {
        __syncthreads();
#pragma unroll
        for (int it = 0; it < (BM * BK) / 2048; ++it) {
            int e = (tid + it * 256) * 8;
            int r = e >> 5, c = e & 31;
            *(uint4*)&As[r][c] = *(const uint4*)(A + (size_t)(m0 + r) * lda + k0 + c);
        }
#pragma unroll
        for (int it = 0; it < (BN * BK) / 2048; ++it) {
            int e = (tid + it * 256) * 8;
            int r = e >> 5, c = e & 31;
            *(uint4*)&Bs[r][c] = *(const uint4*)(Bt + (size_t)(n0 + r) * ldb + k0 + c);
        }
        __syncthreads();
        short8 af[FM], bfr[FN];
#pragma unroll
        for (int i = 0; i < FM; i++) af[i] = *(const short8*)&As[wr * WM + i * 16 + lr][lg * 8];
#pragma unroll
        for (int j = 0; j < FN; j++) bfr[j] = *(const short8*)&Bs[wc * WN + j * 16 + lr][lg * 8];
#pragma unroll
        for (int i = 0; i < FM; i++)
#pragma unroll
            for (int j = 0; j < FN; j++)
                acc[i][j] = __builtin_amdgcn_mfma_f32_16x16x32_bf16(af[i], bfr[j], acc[i][j], 0, 0, 0);
    }
#pragma unroll
    for (int i = 0; i < FM; i++)
#pragma unroll
        for (int j = 0; j < FN; j++)
#pragma unroll
            for (int r = 0; r < 4; r++) {
                int row = m0 + wr * WM + i * 16 + lg * 4 + r;
                int col = n0 + wc * WN + j * 16 + lr;
                store_c(&C[(size_t)row * ldc + col], acc[i][j][r]);
            }
}

// ---------------- flash attention ----------------
// grid: (S/64, B*H), 256 threads. Q rows 64 per block (16/wave), KV tiles of 32.
__global__ __launch_bounds__(256) void mla_attn_kernel(
    const unsigned short* __restrict__ q_all,   // [NTOK][2048], roped
    const unsigned short* __restrict__ kv_all,  // [NTOK][3072], per head: knope[64] | v[128]
    const unsigned short* __restrict__ g1,      // [NTOK][320], cols 256..319 = roped k_r
    unsigned short* __restrict__ attn_out) {    // [NTOK][2048]
    __shared__ __align__(16) unsigned short Ks[32][136];
    __shared__ __align__(16) unsigned short Vst[128][40];  // transposed V: [d][t]
    __shared__ __align__(16) unsigned short Pl[4][16][40];

    const int bh = blockIdx.y, b = bh >> 4, h = bh & 15;
    const int q0 = blockIdx.x * 64;
    const int tid = threadIdx.x, wave = tid >> 6, lane = tid & 63;
    const int lg = lane >> 4, lr = lane & 15;
    const float scale = 0.08838834764831845f;  // 1/sqrt(128)

    // Q fragments (A-operand): rows q0+wave*16+lr, k = kk*32+lg*8
    short8 qf[4];
    const unsigned short* qrow = q_all + (size_t)(b * SS + q0 + wave * 16 + lr) * 2048 + h * 128;
#pragma unroll
    for (int kk = 0; kk < 4; kk++) qf[kk] = *(const short8*)(qrow + kk * 32 + lg * 8);

    f32x4 o[8] = {};
    float m_r[4], l_r[4];
#pragma unroll
    for (int r = 0; r < 4; r++) { m_r[r] = -1e30f; l_r[r] = 0.f; }

    const int tmax = (q0 + 63) >> 5;
    for (int t = 0; t <= tmax; ++t) {
        const int kvbase = b * SS + t * 32;
        __syncthreads();
        // stage K: rows 0..31 (kv), cols 0..127 (64 knope | 64 krope)
#pragma unroll
        for (int it = 0; it < 2; ++it) {
            int e = (tid + it * 256) * 8;
            int r = e >> 7, c = e & 127;
            const unsigned short* src = (c < 64)
                ? kv_all + (size_t)(kvbase + r) * 3072 + h * 192 + c
                : g1 + (size_t)(kvbase + r) * 320 + 256 + (c - 64);
            *(uint4*)&Ks[r][c] = *(const uint4*)src;
        }
        // stage V transposed
#pragma unroll
        for (int it = 0; it < 2; ++it) {
            int e = (tid + it * 256) * 8;
            int r = e >> 7, c = e & 127;
            uint4 v = *(const uint4*)(kv_all + (size_t)(kvbase + r) * 3072 + h * 192 + 64 + c);
            unsigned short* vp = (unsigned short*)&v;
#pragma unroll
            for (int jj = 0; jj < 8; jj++) {
                int j = (jj + lane) & 7;  // rotate to spread LDS banks
                Vst[c + j][r] = vp[j];
            }
        }
        __syncthreads();

        // S = Q K^T (two 16-col fragments)
        f32x4 s[2] = {};
#pragma unroll
        for (int fn = 0; fn < 2; fn++)
#pragma unroll
            for (int kk = 0; kk < 4; kk++) {
                short8 kf = *(const short8*)&Ks[fn * 16 + lr][kk * 32 + lg * 8];
                s[fn] = __builtin_amdgcn_mfma_f32_16x16x32_bf16(qf[kk], kf, s[fn], 0, 0, 0);
            }
        // scale + causal mask
        const int qrow_g = q0 + wave * 16 + lg * 4;
#pragma unroll
        for (int fn = 0; fn < 2; fn++)
#pragma unroll
            for (int r = 0; r < 4; r++) {
                float v = s[fn][r] * scale;
                int kc = t * 32 + fn * 16 + lr;
                if (kc > qrow_g + r) v = -1e30f;
                s[fn][r] = v;
            }
        // online softmax
        float mt[4], alpha[4], psum[4];
        unsigned short pb[2][4];
#pragma unroll
        for (int r = 0; r < 4; r++) {
            mt[r] = fmaxf(s[0][r], s[1][r]);
#pragma unroll
            for (int off = 8; off >= 1; off >>= 1) mt[r] = fmaxf(mt[r], __shfl_xor(mt[r], off, 16));
            float mn = fmaxf(m_r[r], mt[r]);
            alpha[r] = __expf(m_r[r] - mn);
            m_r[r] = mn;
            psum[r] = 0.f;
        }
#pragma unroll
        for (int fn = 0; fn < 2; fn++)
#pragma unroll
            for (int r = 0; r < 4; r++) {
                float p = __expf(s[fn][r] - m_r[r]);
                psum[r] += p;
                pb[fn][r] = f2bf(p);
            }
#pragma unroll
        for (int r = 0; r < 4; r++) {
#pragma unroll
            for (int off = 8; off >= 1; off >>= 1) psum[r] += __shfl_xor(psum[r], off, 16);
            l_r[r] = l_r[r] * alpha[r] + psum[r];
        }
#pragma unroll
        for (int f = 0; f < 8; f++)
#pragma unroll
            for (int r = 0; r < 4; r++) o[f][r] *= alpha[r];
        // write P (wave-private), then PV
#pragma unroll
        for (int fn = 0; fn < 2; fn++)
#pragma unroll
            for (int r = 0; r < 4; r++) Pl[wave][lg * 4 + r][fn * 16 + lr] = pb[fn][r];
        __syncthreads();
        short8 pf = *(const short8*)&Pl[wave][lr][lg * 8];
#pragma unroll
        for (int f = 0; f < 8; f++) {
            short8 vf = *(const short8*)&Vst[f * 16 + lr][lg * 8];
            o[f] = __builtin_amdgcn_mfma_f32_16x16x32_bf16(pf, vf, o[f], 0, 0, 0);
        }
    }

    // epilogue
#pragma unroll
    for (int f = 0; f < 8; f++)
#pragma unroll
        for (int r = 0; r < 4; r++) {
            float val = o[f][r] / l_r[r];
            size_t row = (size_t)(b * SS + q0 + wave * 16 + lg * 4 + r);
            attn_out[row * 2048 + h * 128 + f * 16 + lr] = f2bf(val);
        }
}

// ---------------- launcher ----------------

extern "C" void kernel_launch(void* const* d_in, const int* in_sizes, int n_in,
                              void* d_out, int out_size, void* d_ws, size_t ws_size,
                              hipStream_t stream) {
    const float* x     = (const float*)d_in[0];
    const float* W_dkv = (const float*)d_in[1];
    const float* W_dq  = (const float*)d_in[2];
    const float* W_kr  = (const float*)d_in[3];
    const float* W_qc  = (const float*)d_in[4];
    const float* W_qr  = (const float*)d_in[5];
    const float* W_uk  = (const float*)d_in[6];
    const float* W_uv  = (const float*)d_in[7];
    const float* W_o   = (const float*)d_in[8];
    float* out = (float*)d_out;

    size_t off = 0;
    auto alloc = [&](size_t bytes) {
        void* p = (char*)d_ws + off;
        off = (off + bytes + 255) & ~(size_t)255;
        return p;
    };
    unsigned short* xb    = (unsigned short*)alloc((size_t)NTOK * 2048 * 2);
    unsigned short* WcatT = (unsigned short*)alloc((size_t)320 * 2048 * 2);
    unsigned short* WqT   = (unsigned short*)alloc((size_t)2048 * 128 * 2);
    unsigned short* WkvT  = (unsigned short*)alloc((size_t)3072 * 128 * 2);
    unsigned short* WoT   = (unsigned short*)alloc((size_t)2048 * 2048 * 2);
    unsigned short* g1    = (unsigned short*)alloc((size_t)NTOK * 320 * 2);
    unsigned short* q_all = (unsigned short*)alloc((size_t)NTOK * 2048 * 2);
    unsigned short* kv_all= (unsigned short*)alloc((size_t)NTOK * 3072 * 2);
    unsigned short* attn  = (unsigned short*)alloc((size_t)NTOK * 2048 * 2);

    // conversions
    conv_f32_bf16<<<8192, 256, 0, stream>>>(x, xb, NTOK * 2048);
    build_wcat<<<2560, 256, 0, stream>>>(W_dkv, W_dq, W_kr, WcatT);
    build_wq<<<1024, 256, 0, stream>>>(W_qc, W_qr, WqT);
    build_wkv<<<1536, 256, 0, stream>>>(W_uk, W_uv, WkvT);
    build_wo<<<16384, 256, 0, stream>>>(W_o, WoT);

    // latent GEMM: [4096,2048] x [2048,320] -> g1 [4096,320]
    gemm_bf16_kernel<64, unsigned short><<<dim3(5, 32), 256, 0, stream>>>(
        xb, 2048, WcatT, 2048, g1, 320, NTOK, 320, 2048);
    rope_k_kernel<<<NTOK * 32 / 256, 256, 0, stream>>>(g1);

    // per-head projections (K=128)
    gemm_bf16_kernel<128, unsigned short><<<dim3(16, 32), 256, 0, stream>>>(
        g1 + 128, 320, WqT, 128, q_all, 2048, NTOK, 2048, 128);
    gemm_bf16_kernel<128, unsigned short><<<dim3(24, 32), 256, 0, stream>>>(
        g1, 320, WkvT, 128, kv_all, 3072, NTOK, 3072, 128);
    rope_q_kernel<<<NTOK * 16 * 32 / 256, 256, 0, stream>>>(q_all);

    // attention
    mla_attn_kernel<<<dim3(SS / 64, BB * N_HEAD), 256, 0, stream>>>(q_all, kv_all, g1, attn);

    // output projection -> fp32
    gemm_bf16_kernel<128, float><<<dim3(16, 32), 256, 0, stream>>>(
        attn, 2048, WoT, 2048, out, 2048, NTOK, 2048, 2048);
}

// Round 2
// 273.283 us; speedup vs baseline: 1.9318x; 1.9318x over previous
//
#include <hip/hip_runtime.h>
#include <hip/hip_bf16.h>

typedef __attribute__((ext_vector_type(8))) short short8;
typedef __attribute__((ext_vector_type(4))) float f32x4;

#define N_EMBED 2048
#define N_HEAD 16
#define D_KV 128
#define D_C 64
#define D_R 64
#define D_H 128
#define BB 2
#define SS 2048
#define NTOK (BB*SS)          // 4096

__device__ __forceinline__ unsigned short f2bf(float f) {
    unsigned int b = __builtin_bit_cast(unsigned int, f);
    b += 0x7fffu + ((b >> 16) & 1u);
    return (unsigned short)(b >> 16);
}
__device__ __forceinline__ float bf2f(unsigned short u) {
    unsigned int b = ((unsigned int)u) << 16;
    return __builtin_bit_cast(float, b);
}

// ---------------- conversion / layout kernels ----------------

__global__ void conv_f32_bf16(const float* __restrict__ in, unsigned short* __restrict__ out, int n) {
    int i = (blockIdx.x * 256 + threadIdx.x) * 4;
    if (i >= n) return;
    float4 v = *(const float4*)(in + i);
    ushort4 o;
    o.x = f2bf(v.x); o.y = f2bf(v.y); o.z = f2bf(v.z); o.w = f2bf(v.w);
    *(ushort4*)(out + i) = o;
}

// Wcat_T [320][2048] (output-coalesced; inputs L2-resident)
__global__ void build_wcat(const float* __restrict__ Wdkv, const float* __restrict__ Wdq,
                           const float* __restrict__ Wkr, unsigned short* __restrict__ out) {
    int i = blockIdx.x * 256 + threadIdx.x;          // over 320*2048
    int n = i >> 11, k = i & 2047;
    float v;
    if (n < 128)      v = Wdkv[k * 128 + n];
    else if (n < 256) v = Wdq[k * 128 + (n - 128)];
    else              v = Wkr[k * 64 + (n - 256)];
    out[i] = f2bf(v);
}

// Wq_T [2048][128]: row n = h*128+c; c<64 from W_qc, else W_qr
__global__ void build_wq(const float* __restrict__ Wqc, const float* __restrict__ Wqr,
                         unsigned short* __restrict__ out) {
    int i = blockIdx.x * 256 + threadIdx.x;          // over 2048*128
    int n = i >> 7, k = i & 127;
    int h = n >> 7, c = n & 127;
    float v = (c < 64) ? Wqc[(h * 128 + k) * 64 + c] : Wqr[(h * 128 + k) * 64 + (c - 64)];
    out[i] = f2bf(v);
}

// Wk_T [1024][128]: row n = h*64+c from W_uk
__global__ void build_wk(const float* __restrict__ Wuk, unsigned short* __restrict__ out) {
    int i = blockIdx.x * 256 + threadIdx.x;          // over 1024*128
    int n = i >> 7, k = i & 127;
    int h = n >> 6, c = n & 63;
    out[i] = f2bf(Wuk[(h * 128 + k) * 64 + c]);
}

// WuvT [16][128][128]: WuvT[h][d][k] = W_uv[h][k][d]
__global__ void build_wuvT(const float* __restrict__ Wuv, unsigned short* __restrict__ out) {
    int i = blockIdx.x * 256 + threadIdx.x;          // over 16*128*128
    int h = i >> 14, d = (i >> 7) & 127, k = i & 127;
    out[i] = f2bf(Wuv[(h * 128 + k) * 128 + d]);
}

// Wo_T [2048][2048] via LDS-tiled transpose (64x64 tiles)
__global__ __launch_bounds__(256) void build_wo(const float* __restrict__ Wo, unsigned short* __restrict__ out) {
    __shared__ float tile[64][65];
    const int k0 = blockIdx.x * 64, n0 = blockIdx.y * 64;
    const int tid = threadIdx.x;
    const int tr = tid >> 4, tc = (tid & 15) * 4;
#pragma unroll
    for (int it = 0; it < 4; ++it) {
        int r = it * 16 + tr;
        float4 v = *(const float4*)(Wo + (size_t)(k0 + r) * 2048 + n0 + tc);
        tile[r][tc] = v.x; tile[r][tc + 1] = v.y; tile[r][tc + 2] = v.z; tile[r][tc + 3] = v.w;
    }
    __syncthreads();
#pragma unroll
    for (int it = 0; it < 4; ++it) {
        int r = it * 16 + tr;   // n-local
        ushort4 o;
        o.x = f2bf(tile[tc][r]); o.y = f2bf(tile[tc + 1][r]);
        o.z = f2bf(tile[tc + 2][r]); o.w = f2bf(tile[tc + 3][r]);
        *(ushort4*)(out + (size_t)(n0 + r) * 2048 + k0 + tc) = o;
    }
}

// ---------------- rope ----------------

#define ROPE_COEF (-0.28782313662425575f)  // -ln(10000)/32

__global__ void rope_k_kernel(unsigned short* __restrict__ g1) {
    int i = blockIdx.x * 256 + threadIdx.x;   // NTOK*32
    int j = i & 31, row = i >> 5;
    int pos = row & (SS - 1);
    float freq = __expf(ROPE_COEF * (float)j);
    float a = (float)pos * freq;
    float s, c;
    __sincosf(a, &s, &c);
    unsigned short* p = g1 + (size_t)row * 320 + 256 + 2 * j;
    float x0 = bf2f(p[0]), x1 = bf2f(p[1]);
    p[0] = f2bf(x0 * c - x1 * s);
    p[1] = f2bf(x0 * s + x1 * c);
}

__global__ void rope_q_kernel(unsigned short* __restrict__ q) {
    int i = blockIdx.x * 256 + threadIdx.x;   // NTOK*16*32
    int j = i & 31, h = (i >> 5) & 15, row = i >> 9;
    int pos = row & (SS - 1);
    float freq = __expf(ROPE_COEF * (float)j);
    float a = (float)pos * freq;
    float s, c;
    __sincosf(a, &s, &c);
    unsigned short* p = q + (size_t)row * 2048 + h * 128 + 64 + 2 * j;
    float x0 = bf2f(p[0]), x1 = bf2f(p[1]);
    p[0] = f2bf(x0 * c - x1 * s);
    p[1] = f2bf(x0 * s + x1 * c);
}

// ---------------- GEMM: C[M,N] = A[M,K] * Bt[N,K]^T ----------------

__device__ __forceinline__ void store_c(float* p, float v) { *p = v; }
__device__ __forceinline__ void store_c(unsigned short* p, float v) { *p = f2bf(v); }

template <int BN, typename CT>
__global__ __launch_bounds__(256) void gemm_bf16_kernel(
    const unsigned short* __restrict__ A, int lda,
    const unsigned short* __restrict__ Bt, int ldb,
    CT* __restrict__ C, int ldc,
    int M, int N, int K) {
    constexpr int BM = 128, BK = 32, PAD = 8;
    __shared__ __align__(16) unsigned short As[BM][BK + PAD];
    __shared__ __align__(16) unsigned short Bs[BN][BK + PAD];
    constexpr int WM = 64, WN = BN / 2;
    constexpr int FM = WM / 16, FN = WN / 16;
    const int tid = threadIdx.x, wave = tid >> 6, lane = tid & 63;
    const int wr = wave >> 1, wc = wave & 1;
    const int lg = lane >> 4, lr = lane & 15;
    const int m0 = blockIdx.y * BM, n0 = blockIdx.x * BN;

    f32x4 acc[FM][FN] = {};

    for (int k0 = 0; k0 < K; k0 += BK) {
        __syncthreads();
#pragma unroll
        for (int it = 0; it < (BM * BK) / 2048; ++it) {
            int e = (tid + it * 256) * 8;
            int r = e >> 5, c = e & 31;
            *(uint4*)&As[r][c] = *(const uint4*)(A + (size_t)(m0 + r) * lda + k0 + c);
        }
#pragma unroll
        for (int it = 0; it < (BN * BK) / 2048; ++it) {
            int e = (tid + it * 256) * 8;
            int r = e >> 5, c = e & 31;
            *(uint4*)&Bs[r][c] = *(const uint4*)(Bt + (size_t)(n0 + r) * ldb + k0 + c);
        }
        __syncthreads();
        short8 af[FM], bfr[FN];
#pragma unroll
        for (int i = 0; i < FM; i++) af[i] = *(const short8*)&As[wr * WM + i * 16 + lr][lg * 8];
#pragma unroll
        for (int j = 0; j < FN; j++) bfr[j] = *(const short8*)&Bs[wc * WN + j * 16 + lr][lg * 8];
#pragma unroll
        for (int i = 0; i < FM; i++)
#pragma unroll
            for (int j = 0; j < FN; j++)
                acc[i][j] = __builtin_amdgcn_mfma_f32_16x16x32_bf16(af[i], bfr[j], acc[i][j], 0, 0, 0);
    }
#pragma unroll
    for (int i = 0; i < FM; i++)
#pragma unroll
        for (int j = 0; j < FN; j++)
#pragma unroll
            for (int r = 0; r < 4; r++) {
                int row = m0 + wr * WM + i * 16 + lg * 4 + r;
                int col = n0 + wc * WN + j * 16 + lr;
                store_c(&C[(size_t)row * ldc + col], acc[i][j][r]);
            }
}

// Batched GEMM producing transposed V: v_t[bh][d][s] = sum_k WuvT[h][d][k] * c_kv[b][s][k]
__global__ __launch_bounds__(256) void gemm_vt_kernel(
    const unsigned short* __restrict__ WuvT,   // [16][128][128]
    const unsigned short* __restrict__ g1,     // [NTOK][320], c_kv at cols 0..127
    unsigned short* __restrict__ v_t) {        // [32][128][2048]
    constexpr int BM = 128, BN = 128, BK = 32;
    __shared__ __align__(16) unsigned short As[BM][BK + 8];
    __shared__ __align__(16) unsigned short Bs[BN][BK + 8];
    constexpr int FM = 4, FN = 4;  // 4 waves: wr = wave>>1 (64 rows), wc = wave&1 (64 cols)
    const int tid = threadIdx.x, wave = tid >> 6, lane = tid & 63;
    const int wr = wave >> 1, wc = wave & 1;
    const int lg = lane >> 4, lr = lane & 15;
    const int n0 = blockIdx.x * BN;
    const int bh = blockIdx.y, b = bh >> 4, h = bh & 15;
    const unsigned short* A = WuvT + (size_t)h * 16384;                 // [128][128]
    const unsigned short* Bt = g1 + (size_t)(b * SS) * 320;             // rows: tokens
    unsigned short* C = v_t + (size_t)bh * 128 * 2048;

    f32x4 acc[FM][FN] = {};
    for (int k0 = 0; k0 < 128; k0 += BK) {
        __syncthreads();
#pragma unroll
        for (int it = 0; it < 2; ++it) {
            int e = (tid + it * 256) * 8;
            int r = e >> 5, c = e & 31;
            *(uint4*)&As[r][c] = *(const uint4*)(A + (size_t)r * 128 + k0 + c);
        }
#pragma unroll
        for (int it = 0; it < 2; ++it) {
            int e = (tid + it * 256) * 8;
            int r = e >> 5, c = e & 31;
            *(uint4*)&Bs[r][c] = *(const uint4*)(Bt + (size_t)(n0 + r) * 320 + k0 + c);
        }
        __syncthreads();
        short8 af[FM], bfr[FN];
#pragma unroll
        for (int i = 0; i < FM; i++) af[i] = *(const short8*)&As[wr * 64 + i * 16 + lr][lg * 8];
#pragma unroll
        for (int j = 0; j < FN; j++) bfr[j] = *(const short8*)&Bs[wc * 64 + j * 16 + lr][lg * 8];
#pragma unroll
        for (int i = 0; i < FM; i++)
#pragma unroll
            for (int j = 0; j < FN; j++)
                acc[i][j] = __builtin_amdgcn_mfma_f32_16x16x32_bf16(af[i], bfr[j], acc[i][j], 0, 0, 0);
    }
#pragma unroll
    for (int i = 0; i < FM; i++)
#pragma unroll
        for (int j = 0; j < FN; j++)
#pragma unroll
            for (int r = 0; r < 4; r++) {
                int row = wr * 64 + i * 16 + lg * 4 + r;
                int col = n0 + wc * 64 + j * 16 + lr;
                store_c(&C[(size_t)row * 2048 + col], acc[i][j][r]);
            }
}

// ---------------- flash attention v2 ----------------
// grid: (B*H, S/64), 256 threads. QT=64 (16 rows/wave), KT=64.
__global__ __launch_bounds__(256) void mla_attn_kernel(
    const unsigned short* __restrict__ q_all,   // [NTOK][2048], roped
    const unsigned short* __restrict__ k_all,   // [NTOK][1024] knope per head
    const unsigned short* __restrict__ g1,      // [NTOK][320], cols 256..319 = roped k_r
    const unsigned short* __restrict__ v_t,     // [32][128][2048]
    unsigned short* __restrict__ attn_out) {    // [NTOK][2048]
    __shared__ __align__(16) unsigned short Ks[64][136];
    __shared__ __align__(16) unsigned short Vs[128][72];   // [d][t]
    __shared__ __align__(16) unsigned short Pl[4][16][72]; // wave-private P

    const int bh = blockIdx.x, b = bh >> 4, h = bh & 15;
    const int qb = gridDim.y - 1 - blockIdx.y;   // heavy blocks dispatch first
    const int q0 = qb * 64;
    const int tid = threadIdx.x, wave = tid >> 6, lane = tid & 63;
    const int lg = lane >> 4, lr = lane & 15;
    const float scale = 0.08838834764831845f;  // 1/sqrt(128)

    // Q fragments: rows q0+wave*16+lr, k = kk*32+lg*8
    short8 qf[4];
    const unsigned short* qrow = q_all + (size_t)(b * SS + q0 + wave * 16 + lr) * 2048 + h * 128;
#pragma unroll
    for (int kk = 0; kk < 4; kk++) qf[kk] = *(const short8*)(qrow + kk * 32 + lg * 8);

    f32x4 o[8] = {};
    float m_r[4], l_r[4];
#pragma unroll
    for (int r = 0; r < 4; r++) { m_r[r] = -1e30f; l_r[r] = 0.f; }

    for (int t = 0; t <= qb; ++t) {
        const int kvbase = b * SS + t * 64;
        __syncthreads();
        // stage K: [64][128] = 64 knope | 64 krope
#pragma unroll
        for (int it = 0; it < 4; ++it) {
            int e = (tid + it * 256) * 8;
            int r = e >> 7, c = e & 127;
            const unsigned short* src = (c < 64)
                ? k_all + (size_t)(kvbase + r) * 1024 + h * 64 + c
                : g1 + (size_t)(kvbase + r) * 320 + 256 + (c - 64);
            *(uint4*)&Ks[r][c] = *(const uint4*)src;
        }
        // stage V (already transposed in global): Vs[d][tt]
#pragma unroll
        for (int it = 0; it < 4; ++it) {
            int e = (tid + it * 256) * 8;
            int d = e >> 6, c = e & 63;
            *(uint4*)&Vs[d][c] = *(const uint4*)(v_t + ((size_t)bh * 128 + d) * 2048 + t * 64 + c);
        }
        __syncthreads();

        // S = Q K^T : 4 col-fragments of 16
        f32x4 s[4] = {};
#pragma unroll
        for (int fn = 0; fn < 4; fn++)
#pragma unroll
            for (int kk = 0; kk < 4; kk++) {
                short8 kf = *(const short8*)&Ks[fn * 16 + lr][kk * 32 + lg * 8];
                s[fn] = __builtin_amdgcn_mfma_f32_16x16x32_bf16(qf[kk], kf, s[fn], 0, 0, 0);
            }
        // scale (+ causal mask on diagonal tile only)
#pragma unroll
        for (int fn = 0; fn < 4; fn++)
#pragma unroll
            for (int r = 0; r < 4; r++) s[fn][r] *= scale;
        if (t == qb) {
            const int qr_g = q0 + wave * 16 + lg * 4;
#pragma unroll
            for (int fn = 0; fn < 4; fn++)
#pragma unroll
                for (int r = 0; r < 4; r++) {
                    int kc = t * 64 + fn * 16 + lr;
                    if (kc > qr_g + r) s[fn][r] = -1e30f;
                }
        }
        // online softmax (rows = lg*4+r, 16 lanes share a row)
        float alpha[4];
#pragma unroll
        for (int r = 0; r < 4; r++) {
            float mv = fmaxf(fmaxf(s[0][r], s[1][r]), fmaxf(s[2][r], s[3][r]));
#pragma unroll
            for (int off = 8; off >= 1; off >>= 1) mv = fmaxf(mv, __shfl_xor(mv, off, 16));
            float mn = fmaxf(m_r[r], mv);
            alpha[r] = __expf(m_r[r] - mn);
            m_r[r] = mn;
        }
        float psum[4] = {0.f, 0.f, 0.f, 0.f};
        unsigned short pb[4][4];
#pragma unroll
        for (int fn = 0; fn < 4; fn++)
#pragma unroll
            for (int r = 0; r < 4; r++) {
                float p = __expf(s[fn][r] - m_r[r]);
                psum[r] += p;
                pb[fn][r] = f2bf(p);
            }
#pragma unroll
        for (int r = 0; r < 4; r++) {
#pragma unroll
            for (int off = 8; off >= 1; off >>= 1) psum[r] += __shfl_xor(psum[r], off, 16);
            l_r[r] = l_r[r] * alpha[r] + psum[r];
        }
#pragma unroll
        for (int f = 0; f < 8; f++)
#pragma unroll
            for (int r = 0; r < 4; r++) o[f][r] *= alpha[r];
        // P to wave-private LDS (no barrier needed), then PV
#pragma unroll
        for (int fn = 0; fn < 4; fn++)
#pragma unroll
            for (int r = 0; r < 4; r++) Pl[wave][lg * 4 + r][fn * 16 + lr] = pb[fn][r];
        short8 pf[2];
#pragma unroll
        for (int kk = 0; kk < 2; kk++) pf[kk] = *(const short8*)&Pl[wave][lr][kk * 32 + lg * 8];
#pragma unroll
        for (int f = 0; f < 8; f++)
#pragma unroll
            for (int kk = 0; kk < 2; kk++) {
                short8 vf = *(const short8*)&Vs[f * 16 + lr][kk * 32 + lg * 8];
                o[f] = __builtin_amdgcn_mfma_f32_16x16x32_bf16(pf[kk], vf, o[f], 0, 0, 0);
            }
    }

    // epilogue
#pragma unroll
    for (int f = 0; f < 8; f++)
#pragma unroll
        for (int r = 0; r < 4; r++) {
            float val = o[f][r] / l_r[r];
            size_t row = (size_t)(b * SS + q0 + wave * 16 + lg * 4 + r);
            attn_out[row * 2048 + h * 128 + f * 16 + lr] = f2bf(val);
        }
}

// ---------------- launcher ----------------

extern "C" void kernel_launch(void* const* d_in, const int* in_sizes, int n_in,
                              void* d_out, int out_size, void* d_ws, size_t ws_size,
                              hipStream_t stream) {
    const float* x     = (const float*)d_in[0];
    const float* W_dkv = (const float*)d_in[1];
    const float* W_dq  = (const float*)d_in[2];
    const float* W_kr  = (const float*)d_in[3];
    const float* W_qc  = (const float*)d_in[4];
    const float* W_qr  = (const float*)d_in[5];
    const float* W_uk  = (const float*)d_in[6];
    const float* W_uv  = (const float*)d_in[7];
    const float* W_o   = (const float*)d_in[8];
    float* out = (float*)d_out;

    size_t off = 0;
    auto alloc = [&](size_t bytes) {
        void* p = (char*)d_ws + off;
        off = (off + bytes + 255) & ~(size_t)255;
        return p;
    };
    unsigned short* xb    = (unsigned short*)alloc((size_t)NTOK * 2048 * 2);
    unsigned short* WcatT = (unsigned short*)alloc((size_t)320 * 2048 * 2);
    unsigned short* WqT   = (unsigned short*)alloc((size_t)2048 * 128 * 2);
    unsigned short* WkT   = (unsigned short*)alloc((size_t)1024 * 128 * 2);
    unsigned short* WuvT  = (unsigned short*)alloc((size_t)16 * 128 * 128 * 2);
    unsigned short* WoT   = (unsigned short*)alloc((size_t)2048 * 2048 * 2);
    unsigned short* g1    = (unsigned short*)alloc((size_t)NTOK * 320 * 2);
    unsigned short* q_all = (unsigned short*)alloc((size_t)NTOK * 2048 * 2);
    unsigned short* k_all = (unsigned short*)alloc((size_t)NTOK * 1024 * 2);
    unsigned short* v_tg  = (unsigned short*)alloc((size_t)32 * 128 * 2048 * 2);
    unsigned short* attn  = (unsigned short*)alloc((size_t)NTOK * 2048 * 2);

    // conversions / layout
    conv_f32_bf16<<<8192, 256, 0, stream>>>(x, xb, NTOK * 2048);
    build_wcat<<<2560, 256, 0, stream>>>(W_dkv, W_dq, W_kr, WcatT);
    build_wq<<<1024, 256, 0, stream>>>(W_qc, W_qr, WqT);
    build_wk<<<512, 256, 0, stream>>>(W_uk, WkT);
    build_wuvT<<<1024, 256, 0, stream>>>(W_uv, WuvT);
    build_wo<<<dim3(32, 32), 256, 0, stream>>>(W_o, WoT);

    // latent GEMM: [4096,2048] x [2048,320] -> g1 [4096,320]
    gemm_bf16_kernel<64, unsigned short><<<dim3(5, 32), 256, 0, stream>>>(
        xb, 2048, WcatT, 2048, g1, 320, NTOK, 320, 2048);
    rope_k_kernel<<<NTOK * 32 / 256, 256, 0, stream>>>(g1);

    // per-head projections (K=128)
    gemm_bf16_kernel<128, unsigned short><<<dim3(16, 32), 256, 0, stream>>>(
        g1 + 128, 320, WqT, 128, q_all, 2048, NTOK, 2048, 128);
    gemm_bf16_kernel<128, unsigned short><<<dim3(8, 32), 256, 0, stream>>>(
        g1, 320, WkT, 128, k_all, 1024, NTOK, 1024, 128);
    gemm_vt_kernel<<<dim3(16, 32), 256, 0, stream>>>(WuvT, g1, v_tg);
    rope_q_kernel<<<NTOK * 16 * 32 / 256, 256, 0, stream>>>(q_all);

    // attention
    mla_attn_kernel<<<dim3(BB * N_HEAD, SS / 64), 256, 0, stream>>>(q_all, k_all, g1, v_tg, attn);

    // output projection -> fp32
    gemm_bf16_kernel<128, float><<<dim3(16, 32), 256, 0, stream>>>(
        attn, 2048, WoT, 2048, out, 2048, NTOK, 2048, 2048);
}

// Round 3
// 267.838 us; speedup vs baseline: 1.9710x; 1.0203x over previous
//
#include <hip/hip_runtime.h>
#include <hip/hip_bf16.h>

typedef __attribute__((ext_vector_type(8))) short short8;
typedef __attribute__((ext_vector_type(4))) float f32x4;
typedef __attribute__((ext_vector_type(16))) float f32x16;

#define N_EMBED 2048
#define N_HEAD 16
#define D_KV 128
#define D_C 64
#define D_R 64
#define D_H 128
#define BB 2
#define SS 2048
#define NTOK (BB*SS)          // 4096

__device__ __forceinline__ unsigned short f2bf(float f) {
    unsigned int b = __builtin_bit_cast(unsigned int, f);
    b += 0x7fffu + ((b >> 16) & 1u);
    return (unsigned short)(b >> 16);
}
__device__ __forceinline__ float bf2f(unsigned short u) {
    unsigned int b = ((unsigned int)u) << 16;
    return __builtin_bit_cast(float, b);
}

#define GLOAD_LDS16(gsrc, ldst) __builtin_amdgcn_global_load_lds( \
    (const __attribute__((address_space(1))) void*)(gsrc), \
    (__attribute__((address_space(3))) void*)(ldst), 16, 0, 0)

// ---------------- conversion / layout kernels ----------------

__global__ void conv_f32_bf16(const float* __restrict__ in, unsigned short* __restrict__ out, int n) {
    int i = (blockIdx.x * 256 + threadIdx.x) * 4;
    if (i >= n) return;
    float4 v = *(const float4*)(in + i);
    ushort4 o;
    o.x = f2bf(v.x); o.y = f2bf(v.y); o.z = f2bf(v.z); o.w = f2bf(v.w);
    *(ushort4*)(out + i) = o;
}

// Wcat_T [320][2048]
__global__ void build_wcat(const float* __restrict__ Wdkv, const float* __restrict__ Wdq,
                           const float* __restrict__ Wkr, unsigned short* __restrict__ out) {
    int i = blockIdx.x * 256 + threadIdx.x;
    int n = i >> 11, k = i & 2047;
    float v;
    if (n < 128)      v = Wdkv[k * 128 + n];
    else if (n < 256) v = Wdq[k * 128 + (n - 128)];
    else              v = Wkr[k * 64 + (n - 256)];
    out[i] = f2bf(v);
}

// Wq_T [2048][128]
__global__ void build_wq(const float* __restrict__ Wqc, const float* __restrict__ Wqr,
                         unsigned short* __restrict__ out) {
    int i = blockIdx.x * 256 + threadIdx.x;
    int n = i >> 7, k = i & 127;
    int h = n >> 7, c = n & 127;
    float v = (c < 64) ? Wqc[(h * 128 + k) * 64 + c] : Wqr[(h * 128 + k) * 64 + (c - 64)];
    out[i] = f2bf(v);
}

// Wk_T [1024][128]
__global__ void build_wk(const float* __restrict__ Wuk, unsigned short* __restrict__ out) {
    int i = blockIdx.x * 256 + threadIdx.x;
    int n = i >> 7, k = i & 127;
    int h = n >> 6, c = n & 63;
    out[i] = f2bf(Wuk[(h * 128 + k) * 64 + c]);
}

// WuvT [16][128][128]
__global__ void build_wuvT(const float* __restrict__ Wuv, unsigned short* __restrict__ out) {
    int i = blockIdx.x * 256 + threadIdx.x;
    int h = i >> 14, d = (i >> 7) & 127, k = i & 127;
    out[i] = f2bf(Wuv[(h * 128 + k) * 128 + d]);
}

// Wo_T [2048][2048] via LDS-tiled transpose
__global__ __launch_bounds__(256) void build_wo(const float* __restrict__ Wo, unsigned short* __restrict__ out) {
    __shared__ float tile[64][65];
    const int k0 = blockIdx.x * 64, n0 = blockIdx.y * 64;
    const int tid = threadIdx.x;
    const int tr = tid >> 4, tc = (tid & 15) * 4;
#pragma unroll
    for (int it = 0; it < 4; ++it) {
        int r = it * 16 + tr;
        float4 v = *(const float4*)(Wo + (size_t)(k0 + r) * 2048 + n0 + tc);
        tile[r][tc] = v.x; tile[r][tc + 1] = v.y; tile[r][tc + 2] = v.z; tile[r][tc + 3] = v.w;
    }
    __syncthreads();
#pragma unroll
    for (int it = 0; it < 4; ++it) {
        int r = it * 16 + tr;
        ushort4 o;
        o.x = f2bf(tile[tc][r]); o.y = f2bf(tile[tc + 1][r]);
        o.z = f2bf(tile[tc + 2][r]); o.w = f2bf(tile[tc + 3][r]);
        *(ushort4*)(out + (size_t)(n0 + r) * 2048 + k0 + tc) = o;
    }
}

// ---------------- rope ----------------

#define ROPE_COEF (-0.28782313662425575f)  // -ln(10000)/32

__global__ void rope_k_kernel(unsigned short* __restrict__ g1) {
    int i = blockIdx.x * 256 + threadIdx.x;   // NTOK*32
    int j = i & 31, row = i >> 5;
    int pos = row & (SS - 1);
    float freq = __expf(ROPE_COEF * (float)j);
    float a = (float)pos * freq;
    float s, c;
    __sincosf(a, &s, &c);
    unsigned short* p = g1 + (size_t)row * 320 + 256 + 2 * j;
    float x0 = bf2f(p[0]), x1 = bf2f(p[1]);
    p[0] = f2bf(x0 * c - x1 * s);
    p[1] = f2bf(x0 * s + x1 * c);
}

__global__ void rope_q_kernel(unsigned short* __restrict__ q) {
    int i = blockIdx.x * 256 + threadIdx.x;   // NTOK*16*32
    int j = i & 31, h = (i >> 5) & 15, row = i >> 9;
    int pos = row & (SS - 1);
    float freq = __expf(ROPE_COEF * (float)j);
    float a = (float)pos * freq;
    float s, c;
    __sincosf(a, &s, &c);
    unsigned short* p = q + (size_t)row * 2048 + h * 128 + 64 + 2 * j;
    float x0 = bf2f(p[0]), x1 = bf2f(p[1]);
    p[0] = f2bf(x0 * c - x1 * s);
    p[1] = f2bf(x0 * s + x1 * c);
}

// ---------------- GEMM (m97 structure): C[M,N] = A[M,K] * Bt[N,K]^T ----------------

__device__ __forceinline__ void store_c(float* p, float v) { *p = v; }
__device__ __forceinline__ void store_c(unsigned short* p, float v) { *p = f2bf(v); }

template <int BN, typename CT>
__global__ __launch_bounds__(256) void gemm_bf16_kernel(
    const unsigned short* __restrict__ A, int lda,
    const unsigned short* __restrict__ Bt, int ldb,
    CT* __restrict__ C, int ldc,
    int M, int N, int K) {
    constexpr int BM = 128, BK = 32;
    __shared__ __align__(16) unsigned short As[BM][BK];
    __shared__ __align__(16) unsigned short Bs[BN][BK];
    constexpr int WN = BN / 2;
    constexpr int FM = 4, FN = WN / 16;
    const int tid = threadIdx.x, wave = tid >> 6, lane = tid & 63;
    const int wr = wave >> 1, wc = wave & 1;
    const int lg = lane >> 4, lr = lane & 15;
    const int m0 = blockIdx.y * BM, n0 = blockIdx.x * BN;

    f32x4 acc[FM][FN] = {};

    for (int k0 = 0; k0 < K; k0 += BK) {
        __syncthreads();
#pragma unroll
        for (int it = 0; it < (BM * BK) / 2048; ++it) {
            int e = (tid + it * 256) * 8;
            GLOAD_LDS16(A + (size_t)(m0 + (e >> 5)) * lda + k0 + (e & 31), &As[0][0] + e);
        }
#pragma unroll
        for (int it = 0; it < (BN * BK) / 2048; ++it) {
            int e = (tid + it * 256) * 8;
            GLOAD_LDS16(Bt + (size_t)(n0 + (e >> 5)) * ldb + k0 + (e & 31), &Bs[0][0] + e);
        }
        __syncthreads();
        short8 af[FM], bfr[FN];
#pragma unroll
        for (int i = 0; i < FM; i++) af[i] = *(const short8*)&As[wr * 64 + i * 16 + lr][lg * 8];
#pragma unroll
        for (int j = 0; j < FN; j++) bfr[j] = *(const short8*)&Bs[wc * WN + j * 16 + lr][lg * 8];
#pragma unroll
        for (int i = 0; i < FM; i++)
#pragma unroll
            for (int j = 0; j < FN; j++)
                acc[i][j] = __builtin_amdgcn_mfma_f32_16x16x32_bf16(af[i], bfr[j], acc[i][j], 0, 0, 0);
    }
#pragma unroll
    for (int i = 0; i < FM; i++)
#pragma unroll
        for (int j = 0; j < FN; j++)
#pragma unroll
            for (int r = 0; r < 4; r++) {
                int row = m0 + wr * 64 + i * 16 + lg * 4 + r;
                int col = n0 + wc * WN + j * 16 + lr;
                store_c(&C[(size_t)row * ldc + col], acc[i][j][r]);
            }
}

// Batched GEMM producing transposed V: v_t[bh][d][s]
__global__ __launch_bounds__(256) void gemm_vt_kernel(
    const unsigned short* __restrict__ WuvT,   // [16][128][128]
    const unsigned short* __restrict__ g1,     // [NTOK][320], c_kv cols 0..127
    unsigned short* __restrict__ v_t) {        // [32][128][2048]
    constexpr int BK = 32;
    __shared__ __align__(16) unsigned short As[128][BK];
    __shared__ __align__(16) unsigned short Bs[128][BK];
    const int tid = threadIdx.x, wave = tid >> 6, lane = tid & 63;
    const int wr = wave >> 1, wc = wave & 1;
    const int lg = lane >> 4, lr = lane & 15;
    const int n0 = blockIdx.x * 128;
    const int bh = blockIdx.y, b = bh >> 4, h = bh & 15;
    const unsigned short* A = WuvT + (size_t)h * 16384;
    const unsigned short* Bt = g1 + (size_t)(b * SS) * 320;
    unsigned short* C = v_t + (size_t)bh * 128 * 2048;

    f32x4 acc[4][4] = {};
    for (int k0 = 0; k0 < 128; k0 += BK) {
        __syncthreads();
#pragma unroll
        for (int it = 0; it < 2; ++it) {
            int e = (tid + it * 256) * 8;
            GLOAD_LDS16(A + (size_t)(e >> 5) * 128 + k0 + (e & 31), &As[0][0] + e);
        }
#pragma unroll
        for (int it = 0; it < 2; ++it) {
            int e = (tid + it * 256) * 8;
            GLOAD_LDS16(Bt + (size_t)(n0 + (e >> 5)) * 320 + k0 + (e & 31), &Bs[0][0] + e);
        }
        __syncthreads();
        short8 af[4], bfr[4];
#pragma unroll
        for (int i = 0; i < 4; i++) af[i] = *(const short8*)&As[wr * 64 + i * 16 + lr][lg * 8];
#pragma unroll
        for (int j = 0; j < 4; j++) bfr[j] = *(const short8*)&Bs[wc * 64 + j * 16 + lr][lg * 8];
#pragma unroll
        for (int i = 0; i < 4; i++)
#pragma unroll
            for (int j = 0; j < 4; j++)
                acc[i][j] = __builtin_amdgcn_mfma_f32_16x16x32_bf16(af[i], bfr[j], acc[i][j], 0, 0, 0);
    }
#pragma unroll
    for (int i = 0; i < 4; i++)
#pragma unroll
        for (int j = 0; j < 4; j++)
#pragma unroll
            for (int r = 0; r < 4; r++) {
                int row = wr * 64 + i * 16 + lg * 4 + r;
                int col = n0 + wc * 64 + j * 16 + lr;
                store_c(&C[(size_t)row * 2048 + col], acc[i][j][r]);
            }
}

// ---------------- flash attention v3: 32x32 swapped, in-register softmax ----------------
// 4 waves x 32 q-rows (QT=128), KVT=64, double-buffered LDS, 1 barrier/tile.
// Swapped QK^T: S^T = mfma(A=K, B=Q) -> lane owns q-column (col=lane&31),
//   kv row = (reg&3) + 8*(reg>>2) + 4*(lane>>5)  (per 32-row kv tile).
// PV: O^T = mfma(A=V^T, B=P^T); B-frags built via cvt_pk + permlane32_swap:
//   dword i of a kv-tile holds kv pair base 8*(i>>1)+2*(i&1)+4*hb; B-frag for
//   kstep s=2t+sg needs pairs 16s+8hb+2*j2: own dwords give j2=(0,1), the
//   hi/lo-partner's (via permlane32_swap row1<->row0) give j2=(2,3).
__global__ __launch_bounds__(256, 2) void mla_attn_kernel(
    const unsigned short* __restrict__ q_all,   // [NTOK][2048] roped
    const unsigned short* __restrict__ k_all,   // [NTOK][1024] knope per head
    const unsigned short* __restrict__ g1,      // [NTOK][320], roped k_r at 256
    const unsigned short* __restrict__ v_t,     // [32][128][2048]
    unsigned short* __restrict__ attn_out) {    // [NTOK][2048]
    __shared__ __align__(16) char smem[69632];
    auto Ks = (unsigned short (*)[64][128])smem;            // [2][64][128], chunk-swizzled
    auto Vs = (unsigned short (*)[128][72])(smem + 32768);  // [2][128][72]

    const int id = blockIdx.x;
    const int swz = (id & 7) * 64 + (id >> 3);   // XCD-grouped: 4 bh per XCD
    const int bh = swz >> 4, qb = 15 - (swz & 15);
    const int b = bh >> 4, h = bh & 15;
    const int q0 = qb * 128;
    const int tid = threadIdx.x, wave = tid >> 6, lane = tid & 63;
    const int ql = lane & 31, hb = lane >> 5;
    const int q0w = q0 + wave * 32;
    const int qg = q0w + ql;
    const int nt = 2 * qb + 2;
    const int kvB = b * SS;
    const float sc2 = 0.12751744f;   // (1/sqrt(128)) * log2(e)
    const int xh = ql & 7;

    // Q B-operand frags: col=q (lane-owned), k = 16s + 8*hb + j
    short8 qf[8];
    {
        const unsigned short* qp = q_all + (size_t)(kvB + qg) * 2048 + h * 128 + hb * 8;
#pragma unroll
        for (int s = 0; s < 8; ++s) qf[s] = *(const short8*)(qp + 16 * s);
    }

    f32x16 o[4] = {};
    float m_raw = -3e38f, mb = 0.f, l_r = 0.f;
    uint4 vreg[4];

    auto stageK = [&](int t, int bufi) {
        // linear LDS dest (tid*16B), source chunk pre-swizzled: sc = slot ^ (row&7)
#pragma unroll
        for (int it = 0; it < 4; ++it) {
            int r = (tid >> 4) + it * 16;
            int sc = (tid & 15) ^ (r & 7);
            const unsigned short* src = (sc < 8)
                ? k_all + (size_t)(kvB + t * 64 + r) * 1024 + h * 64 + sc * 8
                : g1 + (size_t)(kvB + t * 64 + r) * 320 + 256 + (sc - 8) * 8;
            GLOAD_LDS16(src, &Ks[bufi][0][0] + tid * 8 + it * 2048);
        }
    };
    auto loadV = [&](int t) {
#pragma unroll
        for (int it = 0; it < 4; ++it) {
            int e = tid * 8 + it * 2048;
            vreg[it] = *(const uint4*)(v_t + ((size_t)bh * 128 + (e >> 6)) * 2048 + t * 64 + (e & 63));
        }
    };
    auto writeV = [&](int bufi) {
#pragma unroll
        for (int it = 0; it < 4; ++it) {
            int e = tid * 8 + it * 2048;
            *(uint4*)&Vs[bufi][e >> 6][e & 63] = vreg[it];
        }
    };

    stageK(0, 0);
    loadV(0);
    writeV(0);
    __syncthreads();

    for (int t = 0; t < nt; ++t) {
        const int cur = t & 1;
        if (t + 1 < nt) { stageK(t + 1, cur ^ 1); loadV(t + 1); }   // async, in flight over compute
        if (t * 64 <= q0w + 31) {
            // ---- S^T = K * Q ----
            f32x16 p0 = {}, p1 = {};
            __builtin_amdgcn_s_setprio(1);
#pragma unroll
            for (int s = 0; s < 8; ++s) {
                int pc = (((2 * s + hb) ^ xh) << 3);   // swizzled chunk ((ql+32)&7 == ql&7)
                short8 k0 = *(const short8*)&Ks[cur][ql][pc];
                short8 k1 = *(const short8*)&Ks[cur][32 + ql][pc];
                p0 = __builtin_amdgcn_mfma_f32_32x32x16_bf16(k0, qf[s], p0, 0, 0, 0);
                p1 = __builtin_amdgcn_mfma_f32_32x32x16_bf16(k1, qf[s], p1, 0, 0, 0);
            }
            __builtin_amdgcn_s_setprio(0);
            const int kv0 = t * 64;
            if (kv0 + 63 > q0w) {   // causal mask (diagonal region only)
#pragma unroll
                for (int r = 0; r < 16; ++r) {
                    int kvg = kv0 + (r & 3) + 8 * (r >> 2) + 4 * hb;
                    if (kvg > qg) p0[r] = -3e38f;
                    if (kvg + 32 > qg) p1[r] = -3e38f;
                }
            }
            // ---- online softmax, in-register ----
            float pm = -3e38f;
#pragma unroll
            for (int r = 0; r < 16; ++r) pm = fmaxf(pm, fmaxf(p0[r], p1[r]));
            pm = fmaxf(pm, __shfl_xor(pm, 32));
            if (__any(pm > m_raw + 64.f)) {   // defer-max (T13): bound e^(64*scale)=287
                float mn = fmaxf(m_raw, pm);
                float alpha = exp2f((m_raw - mn) * sc2);
                m_raw = mn; mb = mn * sc2;
                l_r *= alpha;
#pragma unroll
                for (int dt = 0; dt < 4; ++dt)
#pragma unroll
                    for (int r = 0; r < 16; ++r) o[dt][r] *= alpha;
            }
            float ps = 0.f;
#pragma unroll
            for (int r = 0; r < 16; ++r) {
                p0[r] = exp2f(__builtin_fmaf(p0[r], sc2, -mb));
                p1[r] = exp2f(__builtin_fmaf(p1[r], sc2, -mb));
                ps += p0[r] + p1[r];
            }
            l_r += ps;
            // ---- pack P -> bf16 B-frags (cvt_pk + permlane32_swap) ----
            unsigned int pk0[8], pk1[8];
#pragma unroll
            for (int i = 0; i < 8; ++i) {
                asm("v_cvt_pk_bf16_f32 %0, %1, %2" : "=v"(pk0[i]) : "v"(p0[2 * i]), "v"(p0[2 * i + 1]));
                asm("v_cvt_pk_bf16_f32 %0, %1, %2" : "=v"(pk1[i]) : "v"(p1[2 * i]), "v"(p1[2 * i + 1]));
            }
            uint4 bfr[4];
#pragma unroll
            for (int sg = 0; sg < 2; ++sg) {
                unsigned int x0 = pk0[4 * sg], y0 = pk0[4 * sg + 2];
                asm volatile("v_permlane32_swap_b32 %0, %1" : "+v"(x0), "+v"(y0));
                unsigned int x1 = pk0[4 * sg + 1], y1 = pk0[4 * sg + 3];
                asm volatile("v_permlane32_swap_b32 %0, %1" : "+v"(x1), "+v"(y1));
                bfr[sg] = make_uint4(x0, x1, y0, y1);
                unsigned int x2 = pk1[4 * sg], y2 = pk1[4 * sg + 2];
                asm volatile("v_permlane32_swap_b32 %0, %1" : "+v"(x2), "+v"(y2));
                unsigned int x3 = pk1[4 * sg + 1], y3 = pk1[4 * sg + 3];
                asm volatile("v_permlane32_swap_b32 %0, %1" : "+v"(x3), "+v"(y3));
                bfr[2 + sg] = make_uint4(x2, x3, y2, y3);
            }
            // ---- O^T += V^T * P^T ----
            __builtin_amdgcn_s_setprio(1);
#pragma unroll
            for (int s = 0; s < 4; ++s) {
                short8 pb = __builtin_bit_cast(short8, bfr[s]);
                int vc = 16 * s + 8 * hb;
#pragma unroll
                for (int dt = 0; dt < 4; ++dt) {
                    short8 vf = *(const short8*)&Vs[cur][dt * 32 + ql][vc];
                    o[dt] = __builtin_amdgcn_mfma_f32_32x32x16_bf16(vf, pb, o[dt], 0, 0, 0);
                }
            }
            __builtin_amdgcn_s_setprio(0);
        }
        if (t + 1 < nt) writeV(cur ^ 1);   // late write (T14); buffer safe: readers done at t-1's barrier
        __syncthreads();
    }

    // ---- epilogue: combine l across hi/lo, normalize, transpose via LDS, store ----
    l_r += __shfl_xor(l_r, 32);
    float inv_l = 1.f / l_r;
    unsigned int* ep = (unsigned int*)smem + wave * 2176;   // per-wave [32 q][68 dwords]
#pragma unroll
    for (int dt = 0; dt < 4; ++dt)
#pragma unroll
        for (int r = 0; r < 16; r += 2) {
            float a = o[dt][r] * inv_l, c2 = o[dt][r + 1] * inv_l;
            unsigned int pkv;
            asm("v_cvt_pk_bf16_f32 %0, %1, %2" : "=v"(pkv) : "v"(a), "v"(c2));
            ep[ql * 68 + dt * 16 + ((r & 3) >> 1) + 4 * (r >> 2) + 2 * hb] = pkv;
        }
#pragma unroll
    for (int it = 0; it < 8; ++it) {
        int qr = lane >> 1, ch = (lane & 1) * 8 + it;
        uint4 w = *(uint4*)&ep[qr * 68 + ch * 4];
        *(uint4*)(attn_out + (size_t)(kvB + q0w + qr) * 2048 + h * 128 + ch * 8) = w;
    }
}

// ---------------- launcher ----------------

extern "C" void kernel_launch(void* const* d_in, const int* in_sizes, int n_in,
                              void* d_out, int out_size, void* d_ws, size_t ws_size,
                              hipStream_t stream) {
    const float* x     = (const float*)d_in[0];
    const float* W_dkv = (const float*)d_in[1];
    const float* W_dq  = (const float*)d_in[2];
    const float* W_kr  = (const float*)d_in[3];
    const float* W_qc  = (const float*)d_in[4];
    const float* W_qr  = (const float*)d_in[5];
    const float* W_uk  = (const float*)d_in[6];
    const float* W_uv  = (const float*)d_in[7];
    const float* W_o   = (const float*)d_in[8];
    float* out = (float*)d_out;

    size_t off = 0;
    auto alloc = [&](size_t bytes) {
        void* p = (char*)d_ws + off;
        off = (off + bytes + 255) & ~(size_t)255;
        return p;
    };
    unsigned short* xb    = (unsigned short*)alloc((size_t)NTOK * 2048 * 2);
    unsigned short* WcatT = (unsigned short*)alloc((size_t)320 * 2048 * 2);
    unsigned short* WqT   = (unsigned short*)alloc((size_t)2048 * 128 * 2);
    unsigned short* WkT   = (unsigned short*)alloc((size_t)1024 * 128 * 2);
    unsigned short* WuvT  = (unsigned short*)alloc((size_t)16 * 128 * 128 * 2);
    unsigned short* WoT   = (unsigned short*)alloc((size_t)2048 * 2048 * 2);
    unsigned short* g1    = (unsigned short*)alloc((size_t)NTOK * 320 * 2);
    unsigned short* q_all = (unsigned short*)alloc((size_t)NTOK * 2048 * 2);
    unsigned short* k_all = (unsigned short*)alloc((size_t)NTOK * 1024 * 2);
    unsigned short* v_tg  = (unsigned short*)alloc((size_t)32 * 128 * 2048 * 2);
    unsigned short* attn  = (unsigned short*)alloc((size_t)NTOK * 2048 * 2);

    conv_f32_bf16<<<8192, 256, 0, stream>>>(x, xb, NTOK * 2048);
    build_wcat<<<2560, 256, 0, stream>>>(W_dkv, W_dq, W_kr, WcatT);
    build_wq<<<1024, 256, 0, stream>>>(W_qc, W_qr, WqT);
    build_wk<<<512, 256, 0, stream>>>(W_uk, WkT);
    build_wuvT<<<1024, 256, 0, stream>>>(W_uv, WuvT);
    build_wo<<<dim3(32, 32), 256, 0, stream>>>(W_o, WoT);

    // latent GEMM: [4096,2048] x [2048,320] -> g1
    gemm_bf16_kernel<64, unsigned short><<<dim3(5, 32), 256, 0, stream>>>(
        xb, 2048, WcatT, 2048, g1, 320, NTOK, 320, 2048);
    rope_k_kernel<<<NTOK * 32 / 256, 256, 0, stream>>>(g1);

    // per-head projections (K=128)
    gemm_bf16_kernel<128, unsigned short><<<dim3(16, 32), 256, 0, stream>>>(
        g1 + 128, 320, WqT, 128, q_all, 2048, NTOK, 2048, 128);
    gemm_bf16_kernel<128, unsigned short><<<dim3(8, 32), 256, 0, stream>>>(
        g1, 320, WkT, 128, k_all, 1024, NTOK, 1024, 128);
    gemm_vt_kernel<<<dim3(16, 32), 256, 0, stream>>>(WuvT, g1, v_tg);
    rope_q_kernel<<<NTOK * 16 * 32 / 256, 256, 0, stream>>>(q_all);

    // attention
    mla_attn_kernel<<<512, 256, 0, stream>>>(q_all, k_all, g1, v_tg, attn);

    // output projection -> fp32
    gemm_bf16_kernel<128, float><<<dim3(16, 32), 256, 0, stream>>>(
        attn, 2048, WoT, 2048, out, 2048, NTOK, 2048, 2048);
}

// Round 4
// 239.254 us; speedup vs baseline: 2.2065x; 1.1195x over previous
//
#include <hip/hip_runtime.h>
#include <hip/hip_bf16.h>

typedef __attribute__((ext_vector_type(8))) short short8;
typedef __attribute__((ext_vector_type(4))) float f32x4;
typedef __attribute__((ext_vector_type(16))) float f32x16;

#define N_EMBED 2048
#define N_HEAD 16
#define D_KV 128
#define D_C 64
#define D_R 64
#define D_H 128
#define BB 2
#define SS 2048
#define NTOK (BB*SS)          // 4096

__device__ __forceinline__ unsigned short f2bf(float f) {
    unsigned int b = __builtin_bit_cast(unsigned int, f);
    b += 0x7fffu + ((b >> 16) & 1u);
    return (unsigned short)(b >> 16);
}
__device__ __forceinline__ float bf2f(unsigned short u) {
    unsigned int b = ((unsigned int)u) << 16;
    return __builtin_bit_cast(float, b);
}

#define GLOAD_LDS16(gsrc, ldst) __builtin_amdgcn_global_load_lds( \
    (const __attribute__((address_space(1))) void*)(gsrc), \
    (__attribute__((address_space(3))) void*)(ldst), 16, 0, 0)

// ---------------- conversion / layout kernels ----------------

__global__ void conv_f32_bf16(const float* __restrict__ in, unsigned short* __restrict__ out, int n) {
    int i = (blockIdx.x * 256 + threadIdx.x) * 4;
    if (i >= n) return;
    float4 v = *(const float4*)(in + i);
    ushort4 o;
    o.x = f2bf(v.x); o.y = f2bf(v.y); o.z = f2bf(v.z); o.w = f2bf(v.w);
    *(ushort4*)(out + i) = o;
}

// Wcat_T [320][2048]
__global__ void build_wcat(const float* __restrict__ Wdkv, const float* __restrict__ Wdq,
                           const float* __restrict__ Wkr, unsigned short* __restrict__ out) {
    int i = blockIdx.x * 256 + threadIdx.x;
    int n = i >> 11, k = i & 2047;
    float v;
    if (n < 128)      v = Wdkv[k * 128 + n];
    else if (n < 256) v = Wdq[k * 128 + (n - 128)];
    else              v = Wkr[k * 64 + (n - 256)];
    out[i] = f2bf(v);
}

// Wq_T [2048][128]
__global__ void build_wq(const float* __restrict__ Wqc, const float* __restrict__ Wqr,
                         unsigned short* __restrict__ out) {
    int i = blockIdx.x * 256 + threadIdx.x;
    int n = i >> 7, k = i & 127;
    int h = n >> 7, c = n & 127;
    float v = (c < 64) ? Wqc[(h * 128 + k) * 64 + c] : Wqr[(h * 128 + k) * 64 + (c - 64)];
    out[i] = f2bf(v);
}

// Wk_T [1024][128]
__global__ void build_wk(const float* __restrict__ Wuk, unsigned short* __restrict__ out) {
    int i = blockIdx.x * 256 + threadIdx.x;
    int n = i >> 7, k = i & 127;
    int h = n >> 6, c = n & 63;
    out[i] = f2bf(Wuk[(h * 128 + k) * 64 + c]);
}

// WuvT [16][128][128]
__global__ void build_wuvT(const float* __restrict__ Wuv, unsigned short* __restrict__ out) {
    int i = blockIdx.x * 256 + threadIdx.x;
    int h = i >> 14, d = (i >> 7) & 127, k = i & 127;
    out[i] = f2bf(Wuv[(h * 128 + k) * 128 + d]);
}

// Wo_T [2048][2048] via LDS-tiled transpose
__global__ __launch_bounds__(256) void build_wo(const float* __restrict__ Wo, unsigned short* __restrict__ out) {
    __shared__ float tile[64][65];
    const int k0 = blockIdx.x * 64, n0 = blockIdx.y * 64;
    const int tid = threadIdx.x;
    const int tr = tid >> 4, tc = (tid & 15) * 4;
#pragma unroll
    for (int it = 0; it < 4; ++it) {
        int r = it * 16 + tr;
        float4 v = *(const float4*)(Wo + (size_t)(k0 + r) * 2048 + n0 + tc);
        tile[r][tc] = v.x; tile[r][tc + 1] = v.y; tile[r][tc + 2] = v.z; tile[r][tc + 3] = v.w;
    }
    __syncthreads();
#pragma unroll
    for (int it = 0; it < 4; ++it) {
        int r = it * 16 + tr;
        ushort4 o;
        o.x = f2bf(tile[tc][r]); o.y = f2bf(tile[tc + 1][r]);
        o.z = f2bf(tile[tc + 2][r]); o.w = f2bf(tile[tc + 3][r]);
        *(ushort4*)(out + (size_t)(n0 + r) * 2048 + k0 + tc) = o;
    }
}

// ---------------- rope ----------------

#define ROPE_COEF (-0.28782313662425575f)  // -ln(10000)/32

__global__ void rope_k_kernel(unsigned short* __restrict__ g1) {
    int i = blockIdx.x * 256 + threadIdx.x;   // NTOK*32
    int j = i & 31, row = i >> 5;
    int pos = row & (SS - 1);
    float freq = __expf(ROPE_COEF * (float)j);
    float a = (float)pos * freq;
    float s, c;
    __sincosf(a, &s, &c);
    unsigned short* p = g1 + (size_t)row * 320 + 256 + 2 * j;
    float x0 = bf2f(p[0]), x1 = bf2f(p[1]);
    p[0] = f2bf(x0 * c - x1 * s);
    p[1] = f2bf(x0 * s + x1 * c);
}

__global__ void rope_q_kernel(unsigned short* __restrict__ q) {
    int i = blockIdx.x * 256 + threadIdx.x;   // NTOK*16*32
    int j = i & 31, h = (i >> 5) & 15, row = i >> 9;
    int pos = row & (SS - 1);
    float freq = __expf(ROPE_COEF * (float)j);
    float a = (float)pos * freq;
    float s, c;
    __sincosf(a, &s, &c);
    unsigned short* p = q + (size_t)row * 2048 + h * 128 + 64 + 2 * j;
    float x0 = bf2f(p[0]), x1 = bf2f(p[1]);
    p[0] = f2bf(x0 * c - x1 * s);
    p[1] = f2bf(x0 * s + x1 * c);
}

// ---------------- GEMM (2-phase dbuf): C[M,N] = A[M,K] * Bt[N,K]^T ----------------

__device__ __forceinline__ void store_c(float* p, float v) { *p = v; }
__device__ __forceinline__ void store_c(unsigned short* p, float v) { *p = f2bf(v); }

template <int BN, typename CT>
__global__ __launch_bounds__(256) void gemm_bf16_kernel(
    const unsigned short* __restrict__ A, int lda,
    const unsigned short* __restrict__ Bt, int ldb,
    CT* __restrict__ C, int ldc,
    int M, int N, int K) {
    constexpr int BM = 128, BK = 32;
    __shared__ __align__(16) unsigned short As[2][BM][BK];
    __shared__ __align__(16) unsigned short Bs[2][BN][BK];
    constexpr int WN = BN / 2;
    constexpr int FM = 4, FN = WN / 16;
    const int tid = threadIdx.x, wave = tid >> 6, lane = tid & 63;
    const int wr = wave >> 1, wc = wave & 1;
    const int lg = lane >> 4, lr = lane & 15;
    const int m0 = blockIdx.y * BM, n0 = blockIdx.x * BN;

    f32x4 acc[FM][FN] = {};

    auto stage = [&](int k0, int buf) {
#pragma unroll
        for (int it = 0; it < (BM * BK) / 2048; ++it) {
            int e = (tid + it * 256) * 8;
            GLOAD_LDS16(A + (size_t)(m0 + (e >> 5)) * lda + k0 + (e & 31), &As[buf][0][0] + e);
        }
#pragma unroll
        for (int it = 0; it < (BN * BK) / 2048; ++it) {
            int e = (tid + it * 256) * 8;
            GLOAD_LDS16(Bt + (size_t)(n0 + (e >> 5)) * ldb + k0 + (e & 31), &Bs[buf][0][0] + e);
        }
    };

    const int nk = K / BK;
    stage(0, 0);
    __syncthreads();
    for (int t = 0; t < nk; ++t) {
        const int cur = t & 1;
        if (t + 1 < nk) stage((t + 1) * BK, cur ^ 1);   // overlaps compute(t)
        short8 af[FM], bfr[FN];
#pragma unroll
        for (int i = 0; i < FM; i++) af[i] = *(const short8*)&As[cur][wr * 64 + i * 16 + lr][lg * 8];
#pragma unroll
        for (int j = 0; j < FN; j++) bfr[j] = *(const short8*)&Bs[cur][wc * WN + j * 16 + lr][lg * 8];
#pragma unroll
        for (int i = 0; i < FM; i++)
#pragma unroll
            for (int j = 0; j < FN; j++)
                acc[i][j] = __builtin_amdgcn_mfma_f32_16x16x32_bf16(af[i], bfr[j], acc[i][j], 0, 0, 0);
        __syncthreads();   // drains stage(t+1) loads; Ks safe to reuse
    }
#pragma unroll
    for (int i = 0; i < FM; i++)
#pragma unroll
        for (int j = 0; j < FN; j++)
#pragma unroll
            for (int r = 0; r < 4; r++) {
                int row = m0 + wr * 64 + i * 16 + lg * 4 + r;
                int col = n0 + wc * WN + j * 16 + lr;
                store_c(&C[(size_t)row * ldc + col], acc[i][j][r]);
            }
}

// Batched GEMM producing transposed V: v_t[bh][d][s]
__global__ __launch_bounds__(256) void gemm_vt_kernel(
    const unsigned short* __restrict__ WuvT,   // [16][128][128]
    const unsigned short* __restrict__ g1,     // [NTOK][320], c_kv cols 0..127
    unsigned short* __restrict__ v_t) {        // [32][128][2048]
    constexpr int BK = 32;
    __shared__ __align__(16) unsigned short As[2][128][BK];
    __shared__ __align__(16) unsigned short Bs[2][128][BK];
    const int tid = threadIdx.x, wave = tid >> 6, lane = tid & 63;
    const int wr = wave >> 1, wc = wave & 1;
    const int lg = lane >> 4, lr = lane & 15;
    const int n0 = blockIdx.x * 128;
    const int bh = blockIdx.y, b = bh >> 4, h = bh & 15;
    const unsigned short* A = WuvT + (size_t)h * 16384;
    const unsigned short* Bt = g1 + (size_t)(b * SS) * 320;
    unsigned short* C = v_t + (size_t)bh * 128 * 2048;

    f32x4 acc[4][4] = {};
    auto stage = [&](int k0, int buf) {
#pragma unroll
        for (int it = 0; it < 2; ++it) {
            int e = (tid + it * 256) * 8;
            GLOAD_LDS16(A + (size_t)(e >> 5) * 128 + k0 + (e & 31), &As[buf][0][0] + e);
        }
#pragma unroll
        for (int it = 0; it < 2; ++it) {
            int e = (tid + it * 256) * 8;
            GLOAD_LDS16(Bt + (size_t)(n0 + (e >> 5)) * 320 + k0 + (e & 31), &Bs[buf][0][0] + e);
        }
    };
    stage(0, 0);
    __syncthreads();
    for (int t = 0; t < 4; ++t) {
        const int cur = t & 1;
        if (t + 1 < 4) stage((t + 1) * BK, cur ^ 1);
        short8 af[4], bfr[4];
#pragma unroll
        for (int i = 0; i < 4; i++) af[i] = *(const short8*)&As[cur][wr * 64 + i * 16 + lr][lg * 8];
#pragma unroll
        for (int j = 0; j < 4; j++) bfr[j] = *(const short8*)&Bs[cur][wc * 64 + j * 16 + lr][lg * 8];
#pragma unroll
        for (int i = 0; i < 4; i++)
#pragma unroll
            for (int j = 0; j < 4; j++)
                acc[i][j] = __builtin_amdgcn_mfma_f32_16x16x32_bf16(af[i], bfr[j], acc[i][j], 0, 0, 0);
        __syncthreads();
    }
#pragma unroll
    for (int i = 0; i < 4; i++)
#pragma unroll
        for (int j = 0; j < 4; j++)
#pragma unroll
            for (int r = 0; r < 4; r++) {
                int row = wr * 64 + i * 16 + lg * 4 + r;
                int col = n0 + wc * 64 + j * 16 + lr;
                store_c(&C[(size_t)row * 2048 + col], acc[i][j][r]);
            }
}

// ---------------- flash attention v4: 32x32 swapped + balanced pairing ----------------
// 4 waves x 32 q-rows (QT=128), KVT=64, double-buffered LDS, 1 barrier/tile.
// Block mapping: per-XCD stream s = id>>3; first 32 blocks qb descending,
// second 32 qb ascending -> co-resident CU pairs are complementary (34 tiles each).
__global__ __launch_bounds__(256, 2) void mla_attn_kernel(
    const unsigned short* __restrict__ q_all,   // [NTOK][2048] roped
    const unsigned short* __restrict__ k_all,   // [NTOK][1024] knope per head
    const unsigned short* __restrict__ g1,      // [NTOK][320], roped k_r at 256
    const unsigned short* __restrict__ v_t,     // [32][128][2048]
    unsigned short* __restrict__ attn_out) {    // [NTOK][2048]
    __shared__ __align__(16) char smem[69632];
    auto Ks = (unsigned short (*)[64][128])smem;            // [2][64][128], chunk-swizzled
    auto Vs = (unsigned short (*)[128][72])(smem + 32768);  // [2][128][72]

    const int id = blockIdx.x;
    const int xcd = id & 7, s = id >> 3;
    const int half = s >> 5, sl = s & 31;
    const int qb = half ? (sl & 15) : (15 - (sl & 15));
    const int bh = 4 * xcd + 2 * half + (sl >> 4);
    const int b = bh >> 4, h = bh & 15;
    const int q0 = qb * 128;
    const int tid = threadIdx.x, wave = tid >> 6, lane = tid & 63;
    const int ql = lane & 31, hb = lane >> 5;
    const int q0w = q0 + wave * 32;
    const int qg = q0w + ql;
    const int nt = 2 * qb + 2;
    const int kvB = b * SS;
    const float sc2 = 0.12751744f;   // (1/sqrt(128)) * log2(e)
    const int xh = ql & 7;

    // Q B-operand frags: col=q (lane-owned), k = 16s + 8*hb + j
    short8 qf[8];
    {
        const unsigned short* qp = q_all + (size_t)(kvB + qg) * 2048 + h * 128 + hb * 8;
#pragma unroll
        for (int ss = 0; ss < 8; ++ss) qf[ss] = *(const short8*)(qp + 16 * ss);
    }

    f32x16 o[4] = {};
    float m_raw = -3e38f, mb = 0.f, l_r = 0.f;
    uint4 vreg[4];

    auto stageK = [&](int t, int bufi) {
        // linear LDS dest (tid*16B), source chunk pre-swizzled: sc = slot ^ (row&7)
#pragma unroll
        for (int it = 0; it < 4; ++it) {
            int r = (tid >> 4) + it * 16;
            int sc = (tid & 15) ^ (r & 7);
            const unsigned short* src = (sc < 8)
                ? k_all + (size_t)(kvB + t * 64 + r) * 1024 + h * 64 + sc * 8
                : g1 + (size_t)(kvB + t * 64 + r) * 320 + 256 + (sc - 8) * 8;
            GLOAD_LDS16(src, &Ks[bufi][0][0] + tid * 8 + it * 2048);
        }
    };
    auto loadV = [&](int t) {
#pragma unroll
        for (int it = 0; it < 4; ++it) {
            int e = tid * 8 + it * 2048;
            vreg[it] = *(const uint4*)(v_t + ((size_t)bh * 128 + (e >> 6)) * 2048 + t * 64 + (e & 63));
        }
    };
    auto writeV = [&](int bufi) {
#pragma unroll
        for (int it = 0; it < 4; ++it) {
            int e = tid * 8 + it * 2048;
            *(uint4*)&Vs[bufi][e >> 6][e & 63] = vreg[it];
        }
    };

    stageK(0, 0);
    loadV(0);
    writeV(0);
    __syncthreads();

    for (int t = 0; t < nt; ++t) {
        const int cur = t & 1;
        if (t + 1 < nt) { stageK(t + 1, cur ^ 1); loadV(t + 1); }   // async, in flight over compute
        if (t * 64 <= q0w + 31) {
            // ---- S^T = K * Q ----
            f32x16 p0 = {}, p1 = {};
            __builtin_amdgcn_s_setprio(1);
#pragma unroll
            for (int ss = 0; ss < 8; ++ss) {
                int pc = (((2 * ss + hb) ^ xh) << 3);   // swizzled chunk
                short8 k0 = *(const short8*)&Ks[cur][ql][pc];
                short8 k1 = *(const short8*)&Ks[cur][32 + ql][pc];
                p0 = __builtin_amdgcn_mfma_f32_32x32x16_bf16(k0, qf[ss], p0, 0, 0, 0);
                p1 = __builtin_amdgcn_mfma_f32_32x32x16_bf16(k1, qf[ss], p1, 0, 0, 0);
            }
            __builtin_amdgcn_s_setprio(0);
            const int kv0 = t * 64;
            if (kv0 + 63 > q0w) {   // causal mask (diagonal region only)
#pragma unroll
                for (int r = 0; r < 16; ++r) {
                    int kvg = kv0 + (r & 3) + 8 * (r >> 2) + 4 * hb;
                    if (kvg > qg) p0[r] = -3e38f;
                    if (kvg + 32 > qg) p1[r] = -3e38f;
                }
            }
            // ---- online softmax, in-register ----
            float pm = -3e38f;
#pragma unroll
            for (int r = 0; r < 16; ++r) pm = fmaxf(pm, fmaxf(p0[r], p1[r]));
            pm = fmaxf(pm, __shfl_xor(pm, 32));
            if (__any(pm > m_raw + 64.f)) {   // defer-max (T13)
                float mn = fmaxf(m_raw, pm);
                float alpha = exp2f((m_raw - mn) * sc2);
                m_raw = mn; mb = mn * sc2;
                l_r *= alpha;
#pragma unroll
                for (int dt = 0; dt < 4; ++dt)
#pragma unroll
                    for (int r = 0; r < 16; ++r) o[dt][r] *= alpha;
            }
            float ps = 0.f;
#pragma unroll
            for (int r = 0; r < 16; ++r) {
                p0[r] = exp2f(__builtin_fmaf(p0[r], sc2, -mb));
                p1[r] = exp2f(__builtin_fmaf(p1[r], sc2, -mb));
                ps += p0[r] + p1[r];
            }
            l_r += ps;
            // ---- pack P -> bf16 B-frags (cvt_pk + permlane32_swap) ----
            unsigned int pk0[8], pk1[8];
#pragma unroll
            for (int i = 0; i < 8; ++i) {
                asm("v_cvt_pk_bf16_f32 %0, %1, %2" : "=v"(pk0[i]) : "v"(p0[2 * i]), "v"(p0[2 * i + 1]));
                asm("v_cvt_pk_bf16_f32 %0, %1, %2" : "=v"(pk1[i]) : "v"(p1[2 * i]), "v"(p1[2 * i + 1]));
            }
            uint4 bfr[4];
#pragma unroll
            for (int sg = 0; sg < 2; ++sg) {
                unsigned int x0 = pk0[4 * sg], y0 = pk0[4 * sg + 2];
                asm volatile("v_permlane32_swap_b32 %0, %1" : "+v"(x0), "+v"(y0));
                unsigned int x1 = pk0[4 * sg + 1], y1 = pk0[4 * sg + 3];
                asm volatile("v_permlane32_swap_b32 %0, %1" : "+v"(x1), "+v"(y1));
                bfr[sg] = make_uint4(x0, x1, y0, y1);
                unsigned int x2 = pk1[4 * sg], y2 = pk1[4 * sg + 2];
                asm volatile("v_permlane32_swap_b32 %0, %1" : "+v"(x2), "+v"(y2));
                unsigned int x3 = pk1[4 * sg + 1], y3 = pk1[4 * sg + 3];
                asm volatile("v_permlane32_swap_b32 %0, %1" : "+v"(x3), "+v"(y3));
                bfr[2 + sg] = make_uint4(x2, x3, y2, y3);
            }
            // ---- O^T += V^T * P^T ----
            __builtin_amdgcn_s_setprio(1);
#pragma unroll
            for (int ss = 0; ss < 4; ++ss) {
                short8 pb = __builtin_bit_cast(short8, bfr[ss]);
                int vc = 16 * ss + 8 * hb;
#pragma unroll
                for (int dt = 0; dt < 4; ++dt) {
                    short8 vf = *(const short8*)&Vs[cur][dt * 32 + ql][vc];
                    o[dt] = __builtin_amdgcn_mfma_f32_32x32x16_bf16(vf, pb, o[dt], 0, 0, 0);
                }
            }
            __builtin_amdgcn_s_setprio(0);
        }
        if (t + 1 < nt) writeV(cur ^ 1);   // late write (T14)
        __syncthreads();
    }

    // ---- epilogue: combine l across hi/lo, normalize, transpose via LDS, store ----
    l_r += __shfl_xor(l_r, 32);
    float inv_l = 1.f / l_r;
    unsigned int* ep = (unsigned int*)smem + wave * 2176;   // per-wave [32 q][68 dwords]
#pragma unroll
    for (int dt = 0; dt < 4; ++dt)
#pragma unroll
        for (int r = 0; r < 16; r += 2) {
            float a = o[dt][r] * inv_l, c2 = o[dt][r + 1] * inv_l;
            unsigned int pkv;
            asm("v_cvt_pk_bf16_f32 %0, %1, %2" : "=v"(pkv) : "v"(a), "v"(c2));
            ep[ql * 68 + dt * 16 + ((r & 3) >> 1) + 4 * (r >> 2) + 2 * hb] = pkv;
        }
#pragma unroll
    for (int it = 0; it < 8; ++it) {
        int qr = lane >> 1, ch = (lane & 1) * 8 + it;
        uint4 w = *(uint4*)&ep[qr * 68 + ch * 4];
        *(uint4*)(attn_out + (size_t)(kvB + q0w + qr) * 2048 + h * 128 + ch * 8) = w;
    }
}

// ---------------- launcher ----------------

extern "C" void kernel_launch(void* const* d_in, const int* in_sizes, int n_in,
                              void* d_out, int out_size, void* d_ws, size_t ws_size,
                              hipStream_t stream) {
    const float* x     = (const float*)d_in[0];
    const float* W_dkv = (const float*)d_in[1];
    const float* W_dq  = (const float*)d_in[2];
    const float* W_kr  = (const float*)d_in[3];
    const float* W_qc  = (const float*)d_in[4];
    const float* W_qr  = (const float*)d_in[5];
    const float* W_uk  = (const float*)d_in[6];
    const float* W_uv  = (const float*)d_in[7];
    const float* W_o   = (const float*)d_in[8];
    float* out = (float*)d_out;

    size_t off = 0;
    auto alloc = [&](size_t bytes) {
        void* p = (char*)d_ws + off;
        off = (off + bytes + 255) & ~(size_t)255;
        return p;
    };
    unsigned short* xb    = (unsigned short*)alloc((size_t)NTOK * 2048 * 2);
    unsigned short* WcatT = (unsigned short*)alloc((size_t)320 * 2048 * 2);
    unsigned short* WqT   = (unsigned short*)alloc((size_t)2048 * 128 * 2);
    unsigned short* WkT   = (unsigned short*)alloc((size_t)1024 * 128 * 2);
    unsigned short* WuvT  = (unsigned short*)alloc((size_t)16 * 128 * 128 * 2);
    unsigned short* WoT   = (unsigned short*)alloc((size_t)2048 * 2048 * 2);
    unsigned short* g1    = (unsigned short*)alloc((size_t)NTOK * 320 * 2);
    unsigned short* q_all = (unsigned short*)alloc((size_t)NTOK * 2048 * 2);
    unsigned short* k_all = (unsigned short*)alloc((size_t)NTOK * 1024 * 2);
    unsigned short* v_tg  = (unsigned short*)alloc((size_t)32 * 128 * 2048 * 2);
    unsigned short* attn  = (unsigned short*)alloc((size_t)NTOK * 2048 * 2);

    conv_f32_bf16<<<8192, 256, 0, stream>>>(x, xb, NTOK * 2048);
    build_wcat<<<2560, 256, 0, stream>>>(W_dkv, W_dq, W_kr, WcatT);
    build_wq<<<1024, 256, 0, stream>>>(W_qc, W_qr, WqT);
    build_wk<<<512, 256, 0, stream>>>(W_uk, WkT);
    build_wuvT<<<1024, 256, 0, stream>>>(W_uv, WuvT);
    build_wo<<<dim3(32, 32), 256, 0, stream>>>(W_o, WoT);

    // latent GEMM: [4096,2048] x [2048,320] -> g1
    gemm_bf16_kernel<64, unsigned short><<<dim3(5, 32), 256, 0, stream>>>(
        xb, 2048, WcatT, 2048, g1, 320, NTOK, 320, 2048);
    rope_k_kernel<<<NTOK * 32 / 256, 256, 0, stream>>>(g1);

    // per-head projections (K=128)
    gemm_bf16_kernel<128, unsigned short><<<dim3(16, 32), 256, 0, stream>>>(
        g1 + 128, 320, WqT, 128, q_all, 2048, NTOK, 2048, 128);
    gemm_bf16_kernel<128, unsigned short><<<dim3(8, 32), 256, 0, stream>>>(
        g1, 320, WkT, 128, k_all, 1024, NTOK, 1024, 128);
    gemm_vt_kernel<<<dim3(16, 32), 256, 0, stream>>>(WuvT, g1, v_tg);
    rope_q_kernel<<<NTOK * 16 * 32 / 256, 256, 0, stream>>>(q_all);

    // attention
    mla_attn_kernel<<<512, 256, 0, stream>>>(q_all, k_all, g1, v_tg, attn);

    // output projection -> fp32
    gemm_bf16_kernel<128, float><<<dim3(16, 32), 256, 0, stream>>>(
        attn, 2048, WoT, 2048, out, 2048, NTOK, 2048, 2048);
}